// Round 14
// baseline (42.803 us; speedup 1.0000x reference)
//
#include <hip/hip_runtime.h>

#define FH 128
#define FW 128
#define CPLANE 490                 // 10*7*7 input channels; plane c_in serves bin (ph,pw)
#define NBATCH 4
#define NPLANES (NBATCH * CPLANE)  // 1960
#define NBLK (NPLANES * 2)         // 3920 = 8 * 490 (plane x yhalf)
#define SSCALE 0.0625f
#define YSPLIT 60                  // rois with floor(min sample y) < 60 -> top half
#define NROWS_BOT 68               // rows 60..127
#define LDSF (NROWS_BOT * FW)      // 8704 floats = 34 KB -> 4 blocks/CU

typedef float f32x4 __attribute__((ext_vector_type(4)));

// One block per (plane, y-half). 512 threads, 34KB LDS -> 4 blocks/CU = 2048
// threads/CU: stage phases of 4 blocks tile the CU's HBM share (~95% duty
// vs ~79% at 2 blocks/CU). Top stages rows 0..63, bottom rows 60..127 (halo
// covers the <=4-row bilinear window; +3% fetch).
__global__ __launch_bounds__(512, 8) void psroi_half(const float* __restrict__ feat,
                                                     const float* __restrict__ rois,
                                                     float* __restrict__ out, int R) {
    __shared__ float plane[LDSF];
    int* const lint = (int*)plane;          // compacted roi list (<=2048), pre-commit only
    int* const wtot = (int*)plane + 2048;   // 8 per-wave match counts

    const int tid  = threadIdx.x;
    const int bid  = blockIdx.x;
    const int xcd  = bid & 7;               // XCD chunking: halves+neighbor planes same XCD
    const int jj   = bid >> 3;              // 0..489
    const int pl   = xcd * 245 + (jj >> 1);
    const int half = jj & 1;
    const int b    = pl / CPLANE;
    const int c_in = pl - b * CPLANE;
    const int pw   = c_in % 7;
    const int ph   = (c_in / 7) % 7;
    const int rbase = half ? YSPLIT : 0;
    const int nq    = (half ? NROWS_BOT : 64) * (FW / 4);   // float4 count: 2176 / 2048

    // ---- phase 0: issue NT staging loads (stay in flight through the scan) ----
    const f32x4* __restrict__ src = (const f32x4*)(feat + (size_t)pl * (FH * FW)) + rbase * (FW / 4);
    f32x4 s0 = __builtin_nontemporal_load(src + 0 * 512 + tid);
    f32x4 s1 = __builtin_nontemporal_load(src + 1 * 512 + tid);
    f32x4 s2 = __builtin_nontemporal_load(src + 2 * 512 + tid);
    f32x4 s3 = __builtin_nontemporal_load(src + 3 * 512 + tid);
    f32x4 s4 = {0.f, 0.f, 0.f, 0.f};
    const bool p4 = (2048 + tid) < nq;
    if (p4) s4 = __builtin_nontemporal_load(src + 2048 + tid);

    // ---- phase 1: scan rois (4/thread), ballot-compact batch list ----
    bool m[4];
    int  idx[4];
#pragma unroll
    for (int q = 0; q < 4; ++q) {
        idx[q] = q * 512 + tid;
        m[q] = (idx[q] < R) && ((int)rois[(size_t)idx[q] * 5] == b);
    }
    unsigned long long bl[4];
#pragma unroll
    for (int q = 0; q < 4; ++q) bl[q] = __ballot(m[q]);
    const int w    = tid >> 6;
    const int lane = tid & 63;
    const unsigned long long below = ((unsigned long long)1 << lane) - 1;
    if (lane == 0)
        wtot[w] = __popcll(bl[0]) + __popcll(bl[1]) + __popcll(bl[2]) + __popcll(bl[3]);
    __syncthreads();

    int nb = 0, woff = 0;
#pragma unroll
    for (int ww = 0; ww < 8; ++ww) {
        const int c = wtot[ww];
        if (ww < w) woff += c;
        nb += c;
    }
    // wave-major, then (q, lane) order within wave; list order is irrelevant
    int pos = woff;
#pragma unroll
    for (int q = 0; q < 4; ++q) {
        if (m[q]) lint[pos + __popcll(bl[q] & below)] = idx[q];
        pos += __popcll(bl[q]);
    }
    __syncthreads();

    // ---- phase 2: lift my 8 list entries into named regs (cap 1024 >> nb~512) ----
    const int kb = tid >> 2;
    const int r0 = lint[kb];
    const int r1 = lint[kb + 128];
    const int r2 = lint[kb + 256];
    const int r3 = lint[kb + 384];
    const int r4 = lint[kb + 512];
    const int r5 = lint[kb + 640];
    const int r6 = lint[kb + 768];
    const int r7 = lint[kb + 896];
    __syncthreads();                 // list consumed; plane commit may overwrite

    // ---- phase 3: commit staged rows to LDS (vmcnt wait lands here) ----
    *(f32x4*)(plane + (0 * 512 + tid) * 4) = s0;
    *(f32x4*)(plane + (1 * 512 + tid) * 4) = s1;
    *(f32x4*)(plane + (2 * 512 + tid) * 4) = s2;
    *(f32x4*)(plane + (3 * 512 + tid) * 4) = s3;
    if (p4) *(f32x4*)(plane + (2048 + tid) * 4) = s4;
    __syncthreads();

    // ---- phase 4: gather, 4 lanes per roi, y-half predicate ----
    const int   sub = tid & 3;
    const float sy  = 0.25f + 0.5f * (float)(sub >> 1);
    const float sx  = 0.25f + 0.5f * (float)(sub & 1);

    auto gather = [&](int k, int ri) {
        if (k < nb) {
            const float* roi = rois + (size_t)ri * 5;   // hot 40 KB, cache-resident
            const float x1 = roi[1] * SSCALE;
            const float y1 = roi[2] * SSCALE;
            const float bw = fmaxf(roi[3] * SSCALE - x1, 0.1f) * (1.0f / 7.0f);
            const float bh = fmaxf(roi[4] * SSCALE - y1, 0.1f) * (1.0f / 7.0f);

            // half assignment: min sample y for this bin (lo >= 0 always)
            const float lo = y1 + ((float)ph + 0.25f) * bh;
            const bool mine = (lo < (float)YSPLIT) == (half == 0);
            if (mine) {
                float y = y1 + ((float)ph + sy) * bh;
                y = fminf(fmaxf(y, 0.0f), 127.0f);
                float y0f = floorf(y);
                int   y0  = (int)y0f;
                float ly  = y - y0f;
                if (y0 > 126) { y0 = 126; ly = 1.0f; }   // y==127 -> full weight row 127

                float x = x1 + ((float)pw + sx) * bw;
                x = fminf(fmaxf(x, 0.0f), 127.0f);
                float x0f = floorf(x);
                int   x0  = (int)x0f;
                float lx  = x - x0f;
                if (x0 > 126) { x0 = 126; lx = 1.0f; }

                const float* p = plane + (y0 - rbase) * FW + x0;
                const float v00 = p[0];
                const float v01 = p[1];
                const float v10 = p[FW];
                const float v11 = p[FW + 1];

                const float top = v00 + (v01 - v00) * lx;
                const float bot = v10 + (v11 - v10) * lx;
                float val = top + (bot - top) * ly;

                val += __shfl_xor(val, 1);
                val += __shfl_xor(val, 2);
                if (sub == 0) out[(size_t)ri * CPLANE + c_in] = val * 0.25f;
            }
        }
    };
    gather(kb,       r0);
    gather(kb + 128, r1);
    gather(kb + 256, r2);
    gather(kb + 384, r3);
    gather(kb + 512, r4);
    gather(kb + 640, r5);
    gather(kb + 768, r6);
    gather(kb + 896, r7);
}

extern "C" void kernel_launch(void* const* d_in, const int* in_sizes, int n_in,
                              void* d_out, int out_size, void* d_ws, size_t ws_size,
                              hipStream_t stream) {
    const float* feat = (const float*)d_in[0];
    const float* rois = (const float*)d_in[1];
    float* out = (float*)d_out;

    const int R = in_sizes[1] / 5;   // 2048

    psroi_half<<<NBLK, 512, 0, stream>>>(feat, rois, out, R);
}

// Round 15
// 34.690 us; speedup vs baseline: 1.2339x; 1.2339x over previous
//
#include <hip/hip_runtime.h>

#define FH 128
#define FW 128
#define CPLANE 490                 // 10*7*7 input channels; plane c_in serves bin (ph,pw)
#define NBATCH 4
#define NPLANES (NBATCH * CPLANE)  // 1960 = 8 * 245
#define SSCALE 0.0625f

// ws layout (ints, 33 KB proven-safe band): [0..3]=counts, [4 + b*R + slot]=roi idx
#define WS_CNT  0
#define WS_LIST 4

typedef float f32x4 __attribute__((ext_vector_type(4)));

// ---- kernel A: one block per batch; ballot-compaction, zero atomics --------
__global__ __launch_bounds__(1024) void bucket_rois(const float* __restrict__ rois,
                                                    int R, int* __restrict__ ws) {
    __shared__ int wtot[16];
    const int b   = blockIdx.x;
    const int tid = threadIdx.x;

    const int i0 = tid * 2, i1 = i0 + 1;
    const bool m0 = (i0 < R) && ((int)rois[(size_t)i0 * 5] == b);
    const bool m1 = (i1 < R) && ((int)rois[(size_t)i1 * 5] == b);
    const unsigned long long bl0 = __ballot(m0);
    const unsigned long long bl1 = __ballot(m1);
    const int w    = tid >> 6;
    const int lane = tid & 63;
    const unsigned long long below = ((unsigned long long)1 << lane) - 1;
    if (lane == 0) wtot[w] = __popcll(bl0) + __popcll(bl1);
    __syncthreads();

    int nb = 0, woff = 0;
#pragma unroll
    for (int ww = 0; ww < 16; ++ww) {
        const int c = wtot[ww];
        if (ww < w) woff += c;
        nb += c;
    }
    const int p0 = woff + __popcll(bl0 & below) + __popcll(bl1 & below);
    if (m0) ws[WS_LIST + b * R + p0] = i0;
    if (m1) ws[WS_LIST + b * R + p0 + (m0 ? 1 : 0)] = i1;
    if (tid == 0) ws[WS_CNT + b] = nb;
}

// ---- kernel B: one plane per block, staged in LDS (round-9 structure) ------
// PLAIN loads this round (A/B vs NT): NT bypasses L2 and may throttle TCC
// read efficiency (~4.7 vs 6.3 TB/s). XCD-chunked swizzle kept (write-merge).
__global__ __launch_bounds__(1024, 8) void psroi_plane_lds(const float* __restrict__ feat,
                                                           const float* __restrict__ rois,
                                                           const int* __restrict__ ws,
                                                           float* __restrict__ out, int R) {
    __shared__ float plane[FH * FW];   // exactly 64 KB -> 2 blocks/CU, 32 waves/CU
    const int tid = threadIdx.x;
    const int bid = blockIdx.x;
    const int pl  = (bid & 7) * (NPLANES / 8) + (bid >> 3);  // bijective XCD chunking
    const int b    = pl / CPLANE;
    const int c_in = pl - b * CPLANE;

    // ---- stage plane: 4 coalesced float4 per thread (plain, L2-cached) ----
    const f32x4* __restrict__ src = (const f32x4*)(feat + (size_t)pl * (FH * FW));
    f32x4 s0 = src[0 * 1024 + tid];
    f32x4 s1 = src[1 * 1024 + tid];
    f32x4 s2 = src[2 * 1024 + tid];
    f32x4 s3 = src[3 * 1024 + tid];
    *(f32x4*)(plane + (0 * 1024 + tid) * 4) = s0;
    *(f32x4*)(plane + (1 * 1024 + tid) * 4) = s1;
    *(f32x4*)(plane + (2 * 1024 + tid) * 4) = s2;
    *(f32x4*)(plane + (3 * 1024 + tid) * 4) = s3;
    __syncthreads();

    // ---- gather: 4 lanes per roi (one per bilinear sample) ----
    const int pw = c_in % 7;
    const int ph = (c_in / 7) % 7;
    const int  nb   = ws[WS_CNT + b];
    const int* list = ws + WS_LIST + b * R;

    const int   sub = tid & 3;
    const float sy  = 0.25f + 0.5f * (float)(sub >> 1);
    const float sx  = 0.25f + 0.5f * (float)(sub & 1);

    for (int base = 0; base < nb; base += 256) {
        const int k = base + (tid >> 2);
        if (k < nb) {
            const int ri = list[k];
            const float* roi = rois + (size_t)ri * 5;   // hot 40 KB, cache-resident
            const float x1 = roi[1] * SSCALE;
            const float y1 = roi[2] * SSCALE;
            const float bw = fmaxf(roi[3] * SSCALE - x1, 0.1f) * (1.0f / 7.0f);
            const float bh = fmaxf(roi[4] * SSCALE - y1, 0.1f) * (1.0f / 7.0f);

            float y = y1 + ((float)ph + sy) * bh;
            y = fminf(fmaxf(y, 0.0f), 127.0f);
            float y0f = floorf(y);
            int   y0  = (int)y0f;
            float ly  = y - y0f;
            if (y0 > 126) { y0 = 126; ly = 1.0f; }   // y==127 -> full weight on row 127

            float x = x1 + ((float)pw + sx) * bw;
            x = fminf(fmaxf(x, 0.0f), 127.0f);
            float x0f = floorf(x);
            int   x0  = (int)x0f;
            float lx  = x - x0f;
            if (x0 > 126) { x0 = 126; lx = 1.0f; }

            const float* p = plane + y0 * FW + x0;
            const float v00 = p[0];
            const float v01 = p[1];
            const float v10 = p[FW];
            const float v11 = p[FW + 1];

            const float top = v00 + (v01 - v00) * lx;
            const float bot = v10 + (v11 - v10) * lx;
            float val = top + (bot - top) * ly;

            val += __shfl_xor(val, 1);
            val += __shfl_xor(val, 2);
            if (sub == 0) out[(size_t)ri * CPLANE + c_in] = val * 0.25f;
        }
    }
}

extern "C" void kernel_launch(void* const* d_in, const int* in_sizes, int n_in,
                              void* d_out, int out_size, void* d_ws, size_t ws_size,
                              hipStream_t stream) {
    const float* feat = (const float*)d_in[0];
    const float* rois = (const float*)d_in[1];
    float* out = (float*)d_out;
    int* ws = (int*)d_ws;

    const int R = in_sizes[1] / 5;   // 2048

    bucket_rois<<<NBATCH, 1024, 0, stream>>>(rois, R, ws);
    psroi_plane_lds<<<NPLANES, 1024, 0, stream>>>(feat, rois, ws, out, R);
}